// Round 5
// baseline (299.107 us; speedup 1.0000x reference)
//
#include <hip/hip_runtime.h>
#include <hip/hip_bf16.h>

typedef __attribute__((ext_vector_type(8))) short bf16x8;
typedef __attribute__((ext_vector_type(4))) float f32x4;
typedef __attribute__((ext_vector_type(4))) unsigned int u32x4;

#define BM 128
#define BN 128
#define BK 64
#define NTHREADS 256
#define MTOT 65536

__device__ __forceinline__ short f2bf_s(float f) {
    __hip_bfloat16 b = __float2bfloat16(f);
    return *reinterpret_cast<short*>(&b);
}

#define LOAD_STEP(s) do {                                                    \
    const int k0_ = (s) * BK;                                                \
    const int kc_ = k0_ & 255;                                               \
    const float* as_ = (k0_ < 256) ? xr : xi;                                \
    const float* bs_ = (part == 0) ? ((k0_ < 256) ? wr : wi)                 \
                                   : ((k0_ < 256) ? wi : wr);                \
    _Pragma("unroll")                                                        \
    for (int p_ = 0; p_ < 4; ++p_) {                                         \
        const int row_ = srow + p_ * 32;                                     \
        const float* ga_ = as_ + (size_t)(m0 + row_) * 256 + kc_ + sseg * 8; \
        pa[p_][0] = *(const f32x4*)ga_;                                      \
        pa[p_][1] = *(const f32x4*)(ga_ + 4);                                \
        const float* gb_ = bs_ + (size_t)(h0 + row_) * 256 + kc_ + sseg * 8; \
        pb[p_][0] = *(const f32x4*)gb_;                                      \
        pb[p_][1] = *(const f32x4*)(gb_ + 4);                                \
    }                                                                        \
} while (0)

#define WRITE_STEP(s) do {                                                   \
    const bool neg_ = (part == 0) && ((s) >= 4);                             \
    _Pragma("unroll")                                                        \
    for (int p_ = 0; p_ < 4; ++p_) {                                         \
        const int row_ = srow + p_ * 32;                                     \
        const int slot_ = (row_ * 8 + sseg) ^ (row_ & 7);                    \
        bf16x8 ha_, hb_;                                                     \
        _Pragma("unroll")                                                    \
        for (int j_ = 0; j_ < 4; ++j_) {                                     \
            ha_[j_]     = f2bf_s(pa[p_][0][j_]);                             \
            ha_[4 + j_] = f2bf_s(pa[p_][1][j_]);                             \
            hb_[j_]     = f2bf_s(pb[p_][0][j_]);                             \
            hb_[4 + j_] = f2bf_s(pb[p_][1][j_]);                             \
        }                                                                    \
        if (neg_) {                                                          \
            u32x4 u_ = *(u32x4*)&hb_;                                        \
            u_ = u_ ^ 0x80008000u;                                           \
            hb_ = *(bf16x8*)&u_;                                             \
        }                                                                    \
        *(bf16x8*)(sA + slot_ * 16) = ha_;                                   \
        *(bf16x8*)(sB + slot_ * 16) = hb_;                                   \
    }                                                                        \
} while (0)

__global__ __launch_bounds__(NTHREADS, 2)
void dft256_kernel(const float* __restrict__ xr, const float* __restrict__ xi,
                   const float* __restrict__ wr, const float* __restrict__ wi,
                   float* __restrict__ out)
{
    // bf16 tiles, XOR-swizzled in 16B slots: slot = (row*8 + seg) ^ (row&7)
    __shared__ __align__(16) char sA[BM * BK * 2];
    __shared__ __align__(16) char sB[BN * BK * 2];

    const int tid  = threadIdx.x;
    const int lane = tid & 63;
    const int wv   = tid >> 6;
    const int wrow = wv >> 1;      // wave row 0..1 (64 M-rows each)
    const int wcol = wv & 1;       // wave col 0..1 (64 N-cols each)
    const int fr   = lane & 15;
    const int rg   = lane >> 4;

    // grid remap: the 4 nb-variants of one mb are congruent mod 8 -> same XCD,
    // adjacent in dispatch -> A-tile (256 KB) served from that XCD's L2.
    const int p  = blockIdx.x;
    const int mb = (p & 7) + 8 * (p >> 5);     // 0..511
    const int nb = (p >> 3) & 3;               // 0..3
    const int m0 = mb * BM;
    const int part = nb >> 1;                  // 0 = out_r, 1 = out_i
    const int h0 = (nb & 1) * BN;

    f32x4 acc[4][4];
#pragma unroll
    for (int i = 0; i < 4; ++i)
#pragma unroll
        for (int j = 0; j < 4; ++j)
            acc[i][j] = (f32x4){0.f, 0.f, 0.f, 0.f};

    const int srow = tid >> 3;
    const int sseg = tid & 7;

    f32x4 pa[4][2], pb[4][2];   // prefetch registers (issue-early / write-late)

    LOAD_STEP(0);

#pragma unroll
    for (int ks = 0; ks < 8; ++ks) {
        __syncthreads();            // all waves done reading LDS tile ks-1
        WRITE_STEP(ks);             // vmcnt wait implicit via pa/pb use
        __syncthreads();            // tile ks visible
        if (ks < 7) LOAD_STEP(ks + 1);   // issue next loads; latency hides under MFMA

        // ---- compute: 2 x (8 ds_read_b128 + 16 MFMA) ----
#pragma unroll
        for (int kk = 0; kk < 2; ++kk) {
            const int kbyte = kk * 64 + rg * 16;
            bf16x8 av[4], bv[4];
#pragma unroll
            for (int i = 0; i < 4; ++i) {
                const int row = wrow * 64 + i * 16 + fr;
                av[i] = *(const bf16x8*)(sA + ((row * 128 + kbyte) ^ ((row & 7) << 4)));
            }
#pragma unroll
            for (int j = 0; j < 4; ++j) {
                const int row = wcol * 64 + j * 16 + fr;
                bv[j] = *(const bf16x8*)(sB + ((row * 128 + kbyte) ^ ((row & 7) << 4)));
            }
#pragma unroll
            for (int i = 0; i < 4; ++i)
#pragma unroll
                for (int j = 0; j < 4; ++j)
                    acc[i][j] = __builtin_amdgcn_mfma_f32_16x16x32_bf16(
                        av[i], bv[j], acc[i][j], 0, 0, 0);
        }
    }

    // ---- epilogue: C/D layout col=lane&15, row=(lane>>4)*4+reg ----
    float* obase = out + (size_t)part * ((size_t)MTOT * 256);
#pragma unroll
    for (int i = 0; i < 4; ++i) {
#pragma unroll
        for (int j = 0; j < 4; ++j) {
            const int row = m0 + wrow * 64 + i * 16 + rg * 4;
            const int h = h0 + wcol * 64 + j * 16 + fr;
            float* o = obase + (size_t)row * 256 + h;
#pragma unroll
            for (int r = 0; r < 4; ++r)
                o[(size_t)r * 256] = acc[i][j][r];
        }
    }
}

extern "C" void kernel_launch(void* const* d_in, const int* in_sizes, int n_in,
                              void* d_out, int out_size, void* d_ws, size_t ws_size,
                              hipStream_t stream) {
    const float* xr = (const float*)d_in[0];
    const float* xi = (const float*)d_in[1];
    const float* wr = (const float*)d_in[2];
    const float* wi = (const float*)d_in[3];
    float* out = (float*)d_out;
    dim3 grid((MTOT / BM) * 4);   // 2048 blocks
    dft256_kernel<<<grid, NTHREADS, 0, stream>>>(xr, xi, wr, wi, out);
}

// Round 6
// 247.480 us; speedup vs baseline: 1.2086x; 1.2086x over previous
//
#include <hip/hip_runtime.h>
#include <math.h>

#define NTHR 256
#define ROWS_PER_BLK 16          // 4 waves x 4 groups of 16 lanes
#define NROWS 65536              // 64*128*8
#define BUF_STRIDE 2080          // 16x16 float2 (2048B) + 32B pad (bank shift)

// Radix-16^2 DIT FFT of length 256, forward (W = exp(-i*2pi*jh/256)).
// One 16-lane group handles one row; everything per-lane in registers
// except one rotate-swizzled LDS transpose.
__global__ __launch_bounds__(NTHR)
void dft256_fft_kernel(const float* __restrict__ xr, const float* __restrict__ xi,
                       float* __restrict__ out)
{
    __shared__ float2 w256[256];                       // 2 KB twiddle table
    __shared__ __align__(16) char tbuf[ROWS_PER_BLK * BUF_STRIDE];  // ~33 KB

    const int tid = threadIdx.x;

    // build w256[k] = exp(-i*2*pi*k/256)
    {
        float s, c;
        float ang = -6.283185307179586f * (float)tid / 256.0f;
        sincosf(ang, &s, &c);
        w256[tid] = make_float2(c, s);
    }
    __syncthreads();

    const int r_loc = tid >> 4;        // row within block, 0..15
    const int lid   = tid & 15;        // lane role within 16-group
    const long row  = (long)blockIdx.x * ROWS_PER_BLK + r_loc;

    const float* xrp = xr + row * 256;
    const float* xip = xi + row * 256;

    // ---- load: lane j2=lid holds x[16*t + j2], t=0..15 (64B-coalesced per group)
    float xre[16], xim[16];
#pragma unroll
    for (int t = 0; t < 16; ++t) {
        xre[t] = xrp[16 * t + lid];
        xim[t] = xip[16 * t + lid];
    }

    // ---- w16[k] = w256[16k] into registers (all inner-loop indices static)
    float w16r[16], w16i[16];
#pragma unroll
    for (int k = 0; k < 16; ++k) {
        float2 w = w256[16 * k];
        w16r[k] = w.x; w16i[k] = w.y;
    }

    // ---- stage 1: A[h1] = sum_j1 x[16*j1+j2] * w16[(j1*h1) mod 16]
    float ar[16], ai[16];
#pragma unroll
    for (int h1 = 0; h1 < 16; ++h1) {
        float sr = 0.f, si = 0.f;
#pragma unroll
        for (int t = 0; t < 16; ++t) {
            const int k = (t * h1) & 15;            // compile-time constant
            sr += xre[t] * w16r[k] - xim[t] * w16i[k];
            si += xre[t] * w16i[k] + xim[t] * w16r[k];
        }
        ar[h1] = sr; ai[h1] = si;
    }

    // ---- twiddle: B[h1] = A[h1] * w256[(j2*h1) mod 256]
#pragma unroll
    for (int h1 = 0; h1 < 16; ++h1) {
        float2 w = w256[(lid * h1) & 255];
        float br = ar[h1] * w.x - ai[h1] * w.y;
        float bi = ar[h1] * w.y + ai[h1] * w.x;
        ar[h1] = br; ai[h1] = bi;
    }

    // ---- transpose B within the 16-lane group via LDS (rotate swizzle)
    float2* buf = (float2*)(tbuf + r_loc * BUF_STRIDE);
#pragma unroll
    for (int h1 = 0; h1 < 16; ++h1)
        buf[h1 * 16 + ((lid + h1) & 15)] = make_float2(ar[h1], ai[h1]);

    __syncthreads();   // one barrier per block lifetime; guarantees transpose order

    // lane now owns h1 = lid, holds B[h1][j2=t] for all t
    float cr[16], ci[16];
#pragma unroll
    for (int t = 0; t < 16; ++t) {
        float2 v = buf[lid * 16 + ((t + lid) & 15)];
        cr[t] = v.x; ci[t] = v.y;
    }

    // ---- stage 2 + store: X[h1 + 16*h2] = sum_t B[h1][t] * w16[(t*h2) mod 16]
    float* orow = out + row * 256;                          // real plane
    float* irow = out + (long)NROWS * 256 + row * 256;      // imag plane
#pragma unroll
    for (int h2 = 0; h2 < 16; ++h2) {
        float sr = 0.f, si = 0.f;
#pragma unroll
        for (int t = 0; t < 16; ++t) {
            const int k = (t * h2) & 15;            // compile-time constant
            sr += cr[t] * w16r[k] - ci[t] * w16i[k];
            si += cr[t] * w16i[k] + ci[t] * w16r[k];
        }
        orow[lid + 16 * h2] = sr;   // 16 lanes -> 64B contiguous store
        irow[lid + 16 * h2] = si;
    }
}

extern "C" void kernel_launch(void* const* d_in, const int* in_sizes, int n_in,
                              void* d_out, int out_size, void* d_ws, size_t ws_size,
                              hipStream_t stream) {
    const float* xr = (const float*)d_in[0];
    const float* xi = (const float*)d_in[1];
    // d_in[2]/d_in[3] (w_real/w_imag) unused: twiddles regenerated exactly.
    float* out = (float*)d_out;
    dim3 grid(NROWS / ROWS_PER_BLK);   // 4096 blocks
    dft256_fft_kernel<<<grid, NTHR, 0, stream>>>(xr, xi, out);
}